// Round 8
// baseline (680.889 us; speedup 1.0000x reference)
//
#include <hip/hip_runtime.h>
#include <hip/hip_bf16.h>
#include <math.h>

typedef __bf16 bf16_t;
typedef __bf16 bf16x8 __attribute__((ext_vector_type(8)));
typedef float floatx4 __attribute__((ext_vector_type(4)));

#define S_LEN 4096
#define DMODEL 1024
#define NH 16
#define DK 64
// 0.125 (1/sqrt(dk)) * log2(e): p = exp2(dot * SCALE_LOG2E) == exp(dot/8)
#define SCALE_LOG2E 0.1803368801111204f
#define KPITCH 68   // pitch 68 elems: measured ZERO LDS conflicts in r7 pattern

static __device__ __forceinline__ floatx4 mfma16(bf16x8 a, bf16x8 b, floatx4 c) {
  return __builtin_amdgcn_mfma_f32_16x16x32_bf16(a, b, c, 0, 0, 0);
}

// fp32 -> bf16 elementwise convert (n multiple of 8).
__global__ __launch_bounds__(256) void cvt_f32_bf16(const float* __restrict__ src,
                                                    bf16_t* __restrict__ dst, int n) {
  int i = (blockIdx.x * blockDim.x + threadIdx.x) * 8;
  if (i >= n) return;
  float4 a = *(const float4*)(src + i);
  float4 b = *(const float4*)(src + i + 4);
  bf16x8 v;
  v[0] = (bf16_t)a.x; v[1] = (bf16_t)a.y; v[2] = (bf16_t)a.z; v[3] = (bf16_t)a.w;
  v[4] = (bf16_t)b.x; v[5] = (bf16_t)b.y; v[6] = (bf16_t)b.z; v[7] = (bf16_t)b.w;
  *(bf16x8*)(dst + i) = v;
}

// C = A @ B^T.  A: M x K row-major bf16.  B: N x K row-major bf16.
// TRANS==0: C is M x N row-major (dtype OUT).  TRANS==1: C is N x M (C^T).
template<int TRANS, typename OUT>
__global__ __launch_bounds__(256) void gemm_nt(const bf16_t* __restrict__ A,
                                               const bf16_t* __restrict__ B,
                                               OUT* __restrict__ C,
                                               int M, int N, int K) {
  const int tid  = threadIdx.x;
  const int wid  = tid >> 6;
  const int lane = tid & 63;
  const int lr   = lane & 15;
  const int quad = lane >> 4;
  const int wm = wid >> 1, wn = wid & 1;
  const int m0 = blockIdx.y * 64 + wm * 32;
  const int n0 = blockIdx.x * 64 + wn * 32;

  const bf16_t* aptr0 = A + (size_t)(m0 + lr) * K + quad * 8;
  const bf16_t* aptr1 = aptr0 + (size_t)16 * K;
  const bf16_t* bptr0 = B + (size_t)(n0 + lr) * K + quad * 8;
  const bf16_t* bptr1 = bptr0 + (size_t)16 * K;

  floatx4 acc00 = {0.f, 0.f, 0.f, 0.f};
  floatx4 acc01 = acc00, acc10 = acc00, acc11 = acc00;

#pragma unroll 4
  for (int k = 0; k < K; k += 32) {
    bf16x8 a0 = *(const bf16x8*)(aptr0 + k);
    bf16x8 a1 = *(const bf16x8*)(aptr1 + k);
    bf16x8 b0 = *(const bf16x8*)(bptr0 + k);
    bf16x8 b1 = *(const bf16x8*)(bptr1 + k);
    acc00 = mfma16(a0, b0, acc00);
    acc01 = mfma16(a0, b1, acc01);
    acc10 = mfma16(a1, b0, acc10);
    acc11 = mfma16(a1, b1, acc11);
  }

  floatx4 accs[2][2] = {{acc00, acc01}, {acc10, acc11}};
#pragma unroll
  for (int i = 0; i < 2; ++i) {
#pragma unroll
    for (int j = 0; j < 2; ++j) {
#pragma unroll
      for (int r = 0; r < 4; ++r) {
        int row = m0 + i * 16 + quad * 4 + r;
        int col = n0 + j * 16 + lr;
        OUT v = (OUT)accs[i][j][r];
        if (TRANS == 0)
          C[(size_t)row * N + col] = v;
        else
          C[(size_t)col * M + row] = v;
      }
    }
  }
}

// In-place RoPE on Q and K (S x 1024 bf16). Auto-detects int32/int64 positions.
__global__ __launch_bounds__(256) void rope_kernel(bf16_t* __restrict__ Q,
                                                   bf16_t* __restrict__ K,
                                                   const void* __restrict__ posv) {
  int idx = blockIdx.x * blockDim.x + threadIdx.x;
  if (idx >= S_LEN * 512) return;
  int s   = idx >> 9;
  int rem = idx & 511;
  int h   = rem >> 5;
  int j   = rem & 31;
  size_t off = (size_t)s * DMODEL + h * DK + 2 * j;

  const long long* p64 = (const long long*)posv;
  const int*       p32 = (const int*)posv;
  unsigned long long w0 = (unsigned long long)p64[0];
  unsigned long long w1 = (unsigned long long)p64[1];
  bool is64 = ((w0 >> 32) == 0ull) && ((w1 >> 32) == 0ull);
  int safe_idx = is64 ? s : 0;
  long long v64 = p64[safe_idx];
  float p = is64 ? (float)v64 : (float)p32[s];

  float inv_freq = expf(-(float)j * (9.210340371976184f / 32.0f));
  float ang = p * inv_freq;
  float sn, cs;
  sincosf(ang, &sn, &cs);

  float q1 = (float)Q[off], q2 = (float)Q[off + 1];
  Q[off]     = (bf16_t)(q1 * cs - q2 * sn);
  Q[off + 1] = (bf16_t)(q1 * sn + q2 * cs);

  float k1 = (float)K[off], k2 = (float)K[off + 1];
  K[off]     = (bf16_t)(k1 * cs - k2 * sn);
  K[off + 1] = (bf16_t)(k1 * sn + k2 * cs);
}

// Flash attention, causal, streaming softmax (validated r7), block-cooperative:
// block = 1 head x 64 q-rows (4 waves x 16). K/V 64-chunk staged in LDS shared
// by all 4 waves (coalesced), register-buffered prefetch of next chunk.
// Q,K: S x 1024 row-major. Vt: 1024 x S (V^T, row h*64+dk). Grid: 1024 blocks.
__global__ __launch_bounds__(256) void attn_kernel(const bf16_t* __restrict__ Q,
                                                   const bf16_t* __restrict__ Kb,
                                                   const bf16_t* __restrict__ Vt,
                                                   bf16_t* __restrict__ O) {
  __shared__ __align__(16) bf16_t Kt[64 * KPITCH];      // [kv][dk]
  __shared__ __align__(16) bf16_t Vl[64 * KPITCH];      // [dk][kv]
  __shared__ __align__(16) bf16_t Pl[4][16 * KPITCH];   // per-wave P

  const int tid  = threadIdx.x;
  const int wid  = tid >> 6;
  const int lane = tid & 63;
  const int lr   = lane & 15;
  const int quad = lane >> 4;

  const int bid = blockIdx.x;
  const int h   = bid & 15;
  const int qt  = 63 - (bid >> 4);       // heavy q-tiles scheduled first
  const int q0w = qt * 64 + wid * 16;    // this wave's 16 q-rows

  // Q fragments (A-layout: lane lr = m, quad*8+j = k)
  const bf16_t* Qp = Q + (size_t)(q0w + lr) * DMODEL + h * DK + quad * 8;
  bf16x8 qf0 = *(const bf16x8*)(Qp);        // dk 0..31
  bf16x8 qf1 = *(const bf16x8*)(Qp + 32);   // dk 32..63

  floatx4 o0 = {0.f, 0.f, 0.f, 0.f};
  floatx4 o1 = o0, o2 = o0, o3 = o0;
  float lsum[4] = {0.f, 0.f, 0.f, 0.f};

  // Staging coords: thread t -> row t/4, cols (t%4)*16 .. +15 (32 B)
  const int sr = tid >> 2;
  const int sc = (tid & 3) * 16;
  const bf16_t* Kg = Kb + h * DK + sc;                       // + (kvb+sr)*DMODEL
  const bf16_t* Vg = Vt + (size_t)(h * DK + sr) * S_LEN + sc; // + kvb

  bf16_t* Pw = &Pl[wid][0];

  // Prologue: load chunk 0 into registers
  bf16x8 k0 = *(const bf16x8*)(Kg + (size_t)sr * DMODEL);
  bf16x8 k1 = *(const bf16x8*)(Kg + (size_t)sr * DMODEL + 8);
  bf16x8 v0 = *(const bf16x8*)(Vg);
  bf16x8 v1 = *(const bf16x8*)(Vg + 8);

  for (int c = 0; c <= qt; ++c) {
    // Stage the register-buffered chunk into LDS
    *(bf16x8*)(Kt + sr * KPITCH + sc)     = k0;
    *(bf16x8*)(Kt + sr * KPITCH + sc + 8) = k1;
    *(bf16x8*)(Vl + sr * KPITCH + sc)     = v0;
    *(bf16x8*)(Vl + sr * KPITCH + sc + 8) = v1;
    __syncthreads();

    // Prefetch next chunk into registers (overlaps with compute below)
    if (c < qt) {
      int kvb1 = (c + 1) * 64;
      k0 = *(const bf16x8*)(Kg + (size_t)(kvb1 + sr) * DMODEL);
      k1 = *(const bf16x8*)(Kg + (size_t)(kvb1 + sr) * DMODEL + 8);
      v0 = *(const bf16x8*)(Vg + kvb1);
      v1 = *(const bf16x8*)(Vg + kvb1 + 8);
    }

    const int kvb = c * 64;
    const bool masked = (c == qt);   // only the diagonal chunk

    // QK^T from LDS: 4 kv-fragments x 2 dk-halves -> 8 MFMAs
    floatx4 s[4];
#pragma unroll
    for (int f = 0; f < 4; ++f) {
      const bf16_t* kp = Kt + (f * 16 + lr) * KPITCH + quad * 8;
      floatx4 z = {0.f, 0.f, 0.f, 0.f};
      z = mfma16(qf0, *(const bf16x8*)(kp), z);
      s[f] = mfma16(qf1, *(const bf16x8*)(kp + 32), z);
    }

    // p = exp2(dot * scale*log2e); mask only diagonal chunk; accumulate lsum
#pragma unroll
    for (int f = 0; f < 4; ++f) {
#pragma unroll
      for (int r = 0; r < 4; ++r) {
        float p = exp2f(s[f][r] * SCALE_LOG2E);
        if (masked) {
          int kv   = kvb + f * 16 + lr;
          int qrow = q0w + quad * 4 + r;
          p = (kv <= qrow) ? p : 0.f;
        }
        s[f][r] = p;
        lsum[r] += p;
      }
    }

    // P (C-layout) -> per-wave LDS -> A-layout fragments
#pragma unroll
    for (int f = 0; f < 4; ++f) {
#pragma unroll
      for (int r = 0; r < 4; ++r) {
        Pw[(quad * 4 + r) * KPITCH + f * 16 + lr] = (bf16_t)s[f][r];
      }
    }
    __asm__ volatile("s_waitcnt lgkmcnt(0)" ::: "memory");
    bf16x8 pf0 = *(const bf16x8*)(Pw + lr * KPITCH + quad * 8);        // kv 0..31
    bf16x8 pf1 = *(const bf16x8*)(Pw + lr * KPITCH + 32 + quad * 8);   // kv 32..63

    // O += P @ V from LDS: 4 dk-fragments x 2 kv-halves -> 8 MFMAs
    {
      const bf16_t* vp0 = Vl + (0 * 16 + lr) * KPITCH + quad * 8;
      o0 = mfma16(pf0, *(const bf16x8*)(vp0), o0);
      o0 = mfma16(pf1, *(const bf16x8*)(vp0 + 32), o0);
      const bf16_t* vp1 = Vl + (1 * 16 + lr) * KPITCH + quad * 8;
      o1 = mfma16(pf0, *(const bf16x8*)(vp1), o1);
      o1 = mfma16(pf1, *(const bf16x8*)(vp1 + 32), o1);
      const bf16_t* vp2 = Vl + (2 * 16 + lr) * KPITCH + quad * 8;
      o2 = mfma16(pf0, *(const bf16x8*)(vp2), o2);
      o2 = mfma16(pf1, *(const bf16x8*)(vp2 + 32), o2);
      const bf16_t* vp3 = Vl + (3 * 16 + lr) * KPITCH + quad * 8;
      o3 = mfma16(pf0, *(const bf16x8*)(vp3), o3);
      o3 = mfma16(pf1, *(const bf16x8*)(vp3 + 32), o3);
    }

    __syncthreads();  // all waves done with Kt/Vl before next stage
  }

  // Deferred per-row sum: reduce lsum across the 16 lr lanes (once per wave)
#pragma unroll
  for (int m = 1; m < 16; m <<= 1) {
#pragma unroll
    for (int r = 0; r < 4; ++r) lsum[r] += __shfl_xor(lsum[r], m, 64);
  }

  float inv_li[4];
#pragma unroll
  for (int r = 0; r < 4; ++r) inv_li[r] = 1.0f / lsum[r];

  floatx4 oo[4] = {o0, o1, o2, o3};
#pragma unroll
  for (int dt = 0; dt < 4; ++dt) {
#pragma unroll
    for (int r = 0; r < 4; ++r) {
      int qrow = q0w + quad * 4 + r;
      O[(size_t)qrow * DMODEL + h * DK + dt * 16 + lr] = (bf16_t)(oo[dt][r] * inv_li[r]);
    }
  }
}

extern "C" void kernel_launch(void* const* d_in, const int* in_sizes, int n_in,
                              void* d_out, int out_size, void* d_ws, size_t ws_size,
                              hipStream_t stream) {
  const float* x  = (const float*)d_in[0];
  const float* Wq = (const float*)d_in[1];
  const float* Wk = (const float*)d_in[2];
  const float* Wv = (const float*)d_in[3];
  const float* Wo = (const float*)d_in[4];
  const void* pos = d_in[5];
  float* out = (float*)d_out;

  const size_t NELEM = (size_t)S_LEN * DMODEL;  // 4M elems
  const size_t WELEM = (size_t)DMODEL * DMODEL; // 1M elems

  // Workspace: 34 MB (validated). xb reused as Ob after attn inputs built.
  bf16_t* xb = (bf16_t*)d_ws;   // 8 MB (later Ob)
  bf16_t* Qb = xb + NELEM;      // 8 MB
  bf16_t* Kb = Qb + NELEM;      // 8 MB
  bf16_t* Vt = Kb + NELEM;      // 8 MB
  bf16_t* Wb = Vt + NELEM;      // 2 MB (cycled per weight)
  bf16_t* Ob = xb;

  dim3 blk(256);
  dim3 gg(DMODEL / 64, S_LEN / 64);  // (16, 64)
  int wsblocks = (int)(WELEM / 8 / 256);

  cvt_f32_bf16<<<(int)(NELEM / 8 / 256), blk, 0, stream>>>(x, xb, (int)NELEM);

  cvt_f32_bf16<<<wsblocks, blk, 0, stream>>>(Wq, Wb, (int)WELEM);
  gemm_nt<0, bf16_t><<<gg, blk, 0, stream>>>(xb, Wb, Qb, S_LEN, DMODEL, DMODEL);

  cvt_f32_bf16<<<wsblocks, blk, 0, stream>>>(Wk, Wb, (int)WELEM);
  gemm_nt<0, bf16_t><<<gg, blk, 0, stream>>>(xb, Wb, Kb, S_LEN, DMODEL, DMODEL);

  cvt_f32_bf16<<<wsblocks, blk, 0, stream>>>(Wv, Wb, (int)WELEM);
  gemm_nt<1, bf16_t><<<gg, blk, 0, stream>>>(xb, Wb, Vt, S_LEN, DMODEL, DMODEL);

  int npairs = S_LEN * 512;
  rope_kernel<<<(npairs + 255) / 256, blk, 0, stream>>>(Qb, Kb, pos);

  attn_kernel<<<NH * (S_LEN / 64), blk, 0, stream>>>(Qb, Kb, Vt, Ob);

  cvt_f32_bf16<<<wsblocks, blk, 0, stream>>>(Wo, Wb, (int)WELEM);
  gemm_nt<0, float><<<gg, blk, 0, stream>>>(Ob, Wb, out, S_LEN, DMODEL, DMODEL);
}

// Round 9
// 571.650 us; speedup vs baseline: 1.1911x; 1.1911x over previous
//
#include <hip/hip_runtime.h>
#include <hip/hip_bf16.h>
#include <math.h>

typedef __bf16 bf16_t;
typedef __bf16 bf16x8 __attribute__((ext_vector_type(8)));
typedef float floatx4 __attribute__((ext_vector_type(4)));

#define S_LEN 4096
#define DMODEL 1024
#define NH 16
#define DK 64
// 0.125 (1/sqrt(dk)) * log2(e): p = exp2(dot * SCALE_LOG2E) == exp(dot/8)
#define SCALE_LOG2E 0.1803368801111204f
#define KPITCH 68   // P-transpose pitch: measured ZERO LDS conflicts (r7/r8)
#define OPITCH 65   // Ored pitch: quad stride 260 mod 32 = 4 -> worst 2-way (free)

static __device__ __forceinline__ floatx4 mfma16(bf16x8 a, bf16x8 b, floatx4 c) {
  return __builtin_amdgcn_mfma_f32_16x16x32_bf16(a, b, c, 0, 0, 0);
}

// fp32 -> bf16 elementwise convert (n multiple of 8).
__global__ __launch_bounds__(256) void cvt_f32_bf16(const float* __restrict__ src,
                                                    bf16_t* __restrict__ dst, int n) {
  int i = (blockIdx.x * blockDim.x + threadIdx.x) * 8;
  if (i >= n) return;
  float4 a = *(const float4*)(src + i);
  float4 b = *(const float4*)(src + i + 4);
  bf16x8 v;
  v[0] = (bf16_t)a.x; v[1] = (bf16_t)a.y; v[2] = (bf16_t)a.z; v[3] = (bf16_t)a.w;
  v[4] = (bf16_t)b.x; v[5] = (bf16_t)b.y; v[6] = (bf16_t)b.z; v[7] = (bf16_t)b.w;
  *(bf16x8*)(dst + i) = v;
}

// C = A @ B^T.  A: M x K row-major bf16.  B: N x K row-major bf16.
// TRANS==0: C is M x N row-major (dtype OUT).  TRANS==1: C is N x M (C^T).
template<int TRANS, typename OUT>
__global__ __launch_bounds__(256) void gemm_nt(const bf16_t* __restrict__ A,
                                               const bf16_t* __restrict__ B,
                                               OUT* __restrict__ C,
                                               int M, int N, int K) {
  const int tid  = threadIdx.x;
  const int wid  = tid >> 6;
  const int lane = tid & 63;
  const int lr   = lane & 15;
  const int quad = lane >> 4;
  const int wm = wid >> 1, wn = wid & 1;
  const int m0 = blockIdx.y * 64 + wm * 32;
  const int n0 = blockIdx.x * 64 + wn * 32;

  const bf16_t* aptr0 = A + (size_t)(m0 + lr) * K + quad * 8;
  const bf16_t* aptr1 = aptr0 + (size_t)16 * K;
  const bf16_t* bptr0 = B + (size_t)(n0 + lr) * K + quad * 8;
  const bf16_t* bptr1 = bptr0 + (size_t)16 * K;

  floatx4 acc00 = {0.f, 0.f, 0.f, 0.f};
  floatx4 acc01 = acc00, acc10 = acc00, acc11 = acc00;

#pragma unroll 4
  for (int k = 0; k < K; k += 32) {
    bf16x8 a0 = *(const bf16x8*)(aptr0 + k);
    bf16x8 a1 = *(const bf16x8*)(aptr1 + k);
    bf16x8 b0 = *(const bf16x8*)(bptr0 + k);
    bf16x8 b1 = *(const bf16x8*)(bptr1 + k);
    acc00 = mfma16(a0, b0, acc00);
    acc01 = mfma16(a0, b1, acc01);
    acc10 = mfma16(a1, b0, acc10);
    acc11 = mfma16(a1, b1, acc11);
  }

  floatx4 accs[2][2] = {{acc00, acc01}, {acc10, acc11}};
#pragma unroll
  for (int i = 0; i < 2; ++i) {
#pragma unroll
    for (int j = 0; j < 2; ++j) {
#pragma unroll
      for (int r = 0; r < 4; ++r) {
        int row = m0 + i * 16 + quad * 4 + r;
        int col = n0 + j * 16 + lr;
        OUT v = (OUT)accs[i][j][r];
        if (TRANS == 0)
          C[(size_t)row * N + col] = v;
        else
          C[(size_t)col * M + row] = v;
      }
    }
  }
}

// In-place RoPE on Q and K (S x 1024 bf16). Auto-detects int32/int64 positions.
__global__ __launch_bounds__(256) void rope_kernel(bf16_t* __restrict__ Q,
                                                   bf16_t* __restrict__ K,
                                                   const void* __restrict__ posv) {
  int idx = blockIdx.x * blockDim.x + threadIdx.x;
  if (idx >= S_LEN * 512) return;
  int s   = idx >> 9;
  int rem = idx & 511;
  int h   = rem >> 5;
  int j   = rem & 31;
  size_t off = (size_t)s * DMODEL + h * DK + 2 * j;

  const long long* p64 = (const long long*)posv;
  const int*       p32 = (const int*)posv;
  unsigned long long w0 = (unsigned long long)p64[0];
  unsigned long long w1 = (unsigned long long)p64[1];
  bool is64 = ((w0 >> 32) == 0ull) && ((w1 >> 32) == 0ull);
  int safe_idx = is64 ? s : 0;
  long long v64 = p64[safe_idx];
  float p = is64 ? (float)v64 : (float)p32[s];

  float inv_freq = expf(-(float)j * (9.210340371976184f / 32.0f));
  float ang = p * inv_freq;
  float sn, cs;
  sincosf(ang, &sn, &cs);

  float q1 = (float)Q[off], q2 = (float)Q[off + 1];
  Q[off]     = (bf16_t)(q1 * cs - q2 * sn);
  Q[off + 1] = (bf16_t)(q1 * sn + q2 * cs);

  float k1 = (float)K[off], k2 = (float)K[off + 1];
  K[off]     = (bf16_t)(k1 * cs - k2 * sn);
  K[off + 1] = (bf16_t)(k1 * sn + k2 * cs);
}

// Flash attention, causal, streaming softmax (validated r7). KV-PARALLEL:
// block = (head, 16 q-rows); the 4 waves split the kv chunk list round-robin
// (streaming softmax partials are purely additive: O=ΣO_w, l=Σl_w), run the
// r7-style direct-gather loop with NO barriers, then merge once through LDS.
// Q,K: S x 1024 row-major. Vt: 1024 x S (V^T). Grid: NH*(S/16) = 4096 blocks.
__global__ __launch_bounds__(256) void attn_kernel(const bf16_t* __restrict__ Q,
                                                   const bf16_t* __restrict__ Kb,
                                                   const bf16_t* __restrict__ Vt,
                                                   bf16_t* __restrict__ O) {
  __shared__ __align__(16) bf16_t Pl[4][16 * KPITCH];      // per-wave P transpose
  __shared__ float Ored[4][16][OPITCH];                    // per-wave O partials
  __shared__ float lsFull[4][16];                          // per-wave row sums

  const int tid  = threadIdx.x;
  const int wid  = tid >> 6;
  const int lane = tid & 63;
  const int lr   = lane & 15;
  const int quad = lane >> 4;

  const int bid = blockIdx.x;
  const int h   = bid & 15;
  const int qt  = 255 - (bid >> 4);     // heavy q-tiles scheduled first
  const int q0  = qt * 16;
  const int total_ch = (qt >> 2) + 1;   // 64-kv chunks covering [0, q0+16)

  // Q fragments (A-layout: lane lr = m, quad*8+j = k)
  const bf16_t* Qp = Q + (size_t)(q0 + lr) * DMODEL + h * DK + quad * 8;
  bf16x8 qf0 = *(const bf16x8*)(Qp);
  bf16x8 qf1 = *(const bf16x8*)(Qp + 32);

  floatx4 o0 = {0.f, 0.f, 0.f, 0.f};
  floatx4 o1 = o0, o2 = o0, o3 = o0;
  float lsum[4] = {0.f, 0.f, 0.f, 0.f};

  const bf16_t* Kh = Kb + h * DK;
  const bf16_t* Vh = Vt + (size_t)h * DK * S_LEN;
  bf16_t* Pw = &Pl[wid][0];

  // Round-robin kv chunks across the block's 4 waves; no barriers in loop.
  for (int c = wid; c < total_ch; c += 4) {
    const int kvb = c * 64;
    const bool masked = (c == total_ch - 1);   // only the diagonal chunk

    // QK^T: 4 kv-fragments x 2 dk-halves -> 8 MFMAs (direct global gathers)
    floatx4 s[4];
#pragma unroll
    for (int f = 0; f < 4; ++f) {
      const bf16_t* Kf = Kh + (size_t)(kvb + f * 16 + lr) * DMODEL + quad * 8;
      floatx4 z = {0.f, 0.f, 0.f, 0.f};
      z = mfma16(qf0, *(const bf16x8*)(Kf), z);
      s[f] = mfma16(qf1, *(const bf16x8*)(Kf + 32), z);
    }

    // p = exp2(dot * scale*log2e); mask only diagonal chunk; accumulate lsum
#pragma unroll
    for (int f = 0; f < 4; ++f) {
#pragma unroll
      for (int r = 0; r < 4; ++r) {
        float p = exp2f(s[f][r] * SCALE_LOG2E);
        if (masked) {
          int kv   = kvb + f * 16 + lr;
          int qrow = q0 + quad * 4 + r;
          p = (kv <= qrow) ? p : 0.f;
        }
        s[f][r] = p;
        lsum[r] += p;
      }
    }

    // P (C-layout) -> per-wave LDS -> A-layout fragments (lgkmcnt fence only)
#pragma unroll
    for (int f = 0; f < 4; ++f) {
#pragma unroll
      for (int r = 0; r < 4; ++r) {
        Pw[(quad * 4 + r) * KPITCH + f * 16 + lr] = (bf16_t)s[f][r];
      }
    }
    __asm__ volatile("s_waitcnt lgkmcnt(0)" ::: "memory");
    bf16x8 pf0 = *(const bf16x8*)(Pw + lr * KPITCH + quad * 8);
    bf16x8 pf1 = *(const bf16x8*)(Pw + lr * KPITCH + 32 + quad * 8);

    // O += P @ V (direct from Vt: contiguous along kv)
    const bf16_t* vp = Vh + (size_t)lr * S_LEN + kvb + quad * 8;
    o0 = mfma16(pf0, *(const bf16x8*)(vp), o0);
    o0 = mfma16(pf1, *(const bf16x8*)(vp + 32), o0);
    const bf16_t* vp1 = vp + (size_t)16 * S_LEN;
    o1 = mfma16(pf0, *(const bf16x8*)(vp1), o1);
    o1 = mfma16(pf1, *(const bf16x8*)(vp1 + 32), o1);
    const bf16_t* vp2 = vp + (size_t)32 * S_LEN;
    o2 = mfma16(pf0, *(const bf16x8*)(vp2), o2);
    o2 = mfma16(pf1, *(const bf16x8*)(vp2 + 32), o2);
    const bf16_t* vp3 = vp + (size_t)48 * S_LEN;
    o3 = mfma16(pf0, *(const bf16x8*)(vp3), o3);
    o3 = mfma16(pf1, *(const bf16x8*)(vp3 + 32), o3);
  }

  // Wave-local reduce of lsum over the 16 lr lanes
#pragma unroll
  for (int m = 1; m < 16; m <<= 1) {
#pragma unroll
    for (int r = 0; r < 4; ++r) lsum[r] += __shfl_xor(lsum[r], m, 64);
  }

  // Publish partials to LDS
  floatx4 oo[4] = {o0, o1, o2, o3};
#pragma unroll
  for (int dt = 0; dt < 4; ++dt) {
#pragma unroll
    for (int r = 0; r < 4; ++r) {
      Ored[wid][quad * 4 + r][dt * 16 + lr] = oo[dt][r];
    }
  }
  if (lr == 0) {
#pragma unroll
    for (int r = 0; r < 4; ++r) lsFull[wid][quad * 4 + r] = lsum[r];
  }
  __syncthreads();

  // Merge: wave wid handles rows wid*4..wid*4+3; lane = column 0..63
#pragma unroll
  for (int rr = 0; rr < 4; ++rr) {
    int row = wid * 4 + rr;
    float acc = Ored[0][row][lane] + Ored[1][row][lane] +
                Ored[2][row][lane] + Ored[3][row][lane];
    float l = lsFull[0][row] + lsFull[1][row] + lsFull[2][row] + lsFull[3][row];
    O[(size_t)(q0 + row) * DMODEL + h * DK + lane] = (bf16_t)(acc / l);
  }
}

extern "C" void kernel_launch(void* const* d_in, const int* in_sizes, int n_in,
                              void* d_out, int out_size, void* d_ws, size_t ws_size,
                              hipStream_t stream) {
  const float* x  = (const float*)d_in[0];
  const float* Wq = (const float*)d_in[1];
  const float* Wk = (const float*)d_in[2];
  const float* Wv = (const float*)d_in[3];
  const float* Wo = (const float*)d_in[4];
  const void* pos = d_in[5];
  float* out = (float*)d_out;

  const size_t NELEM = (size_t)S_LEN * DMODEL;  // 4M elems
  const size_t WELEM = (size_t)DMODEL * DMODEL; // 1M elems

  // Workspace: 34 MB (validated). xb reused as Ob after attn inputs built.
  bf16_t* xb = (bf16_t*)d_ws;   // 8 MB (later Ob)
  bf16_t* Qb = xb + NELEM;      // 8 MB
  bf16_t* Kb = Qb + NELEM;      // 8 MB
  bf16_t* Vt = Kb + NELEM;      // 8 MB
  bf16_t* Wb = Vt + NELEM;      // 2 MB (cycled per weight)
  bf16_t* Ob = xb;

  dim3 blk(256);
  dim3 gg(DMODEL / 64, S_LEN / 64);  // (16, 64)
  int wsblocks = (int)(WELEM / 8 / 256);

  cvt_f32_bf16<<<(int)(NELEM / 8 / 256), blk, 0, stream>>>(x, xb, (int)NELEM);

  cvt_f32_bf16<<<wsblocks, blk, 0, stream>>>(Wq, Wb, (int)WELEM);
  gemm_nt<0, bf16_t><<<gg, blk, 0, stream>>>(xb, Wb, Qb, S_LEN, DMODEL, DMODEL);

  cvt_f32_bf16<<<wsblocks, blk, 0, stream>>>(Wk, Wb, (int)WELEM);
  gemm_nt<0, bf16_t><<<gg, blk, 0, stream>>>(xb, Wb, Kb, S_LEN, DMODEL, DMODEL);

  cvt_f32_bf16<<<wsblocks, blk, 0, stream>>>(Wv, Wb, (int)WELEM);
  gemm_nt<1, bf16_t><<<gg, blk, 0, stream>>>(xb, Wb, Vt, S_LEN, DMODEL, DMODEL);

  int npairs = S_LEN * 512;
  rope_kernel<<<(npairs + 255) / 256, blk, 0, stream>>>(Qb, Kb, pos);

  // kv-parallel: 4096 blocks (one per head x q-tile), 4 waves split kv
  attn_kernel<<<NH * (S_LEN / 16), blk, 0, stream>>>(Qb, Kb, Vt, Ob);

  cvt_f32_bf16<<<wsblocks, blk, 0, stream>>>(Wo, Wb, (int)WELEM);
  gemm_nt<0, float><<<gg, blk, 0, stream>>>(Ob, Wb, out, S_LEN, DMODEL, DMODEL);
}

// Round 10
// 411.677 us; speedup vs baseline: 1.6539x; 1.3886x over previous
//
#include <hip/hip_runtime.h>
#include <hip/hip_bf16.h>
#include <math.h>

typedef __bf16 bf16_t;
typedef __bf16 bf16x8 __attribute__((ext_vector_type(8)));
typedef float floatx4 __attribute__((ext_vector_type(4)));

#define S_LEN 4096
#define DMODEL 1024
#define NH 16
#define DK 64
// 0.125 (1/sqrt(dk)) * log2(e): p = exp2(dot * SCALE_LOG2E) == exp(dot/8)
#define SCALE_LOG2E 0.1803368801111204f
#define KPITCH 68   // attn P-transpose pitch: measured ZERO LDS conflicts (r7-r9)
#define OPITCH 65   // attn Ored pitch: worst 2-way (free)

// GEMM tile params
#define BM 128
#define BN 64
#define BK 32
#define APITCH 40   // 32+8 elems = 80 B: 16B-aligned, bank stride 20 -> max 2-way (free)

static __device__ __forceinline__ floatx4 mfma16(bf16x8 a, bf16x8 b, floatx4 c) {
  return __builtin_amdgcn_mfma_f32_16x16x32_bf16(a, b, c, 0, 0, 0);
}

// fp32 -> bf16 elementwise convert (n multiple of 8).
__global__ __launch_bounds__(256) void cvt_f32_bf16(const float* __restrict__ src,
                                                    bf16_t* __restrict__ dst, int n) {
  int i = (blockIdx.x * blockDim.x + threadIdx.x) * 8;
  if (i >= n) return;
  float4 a = *(const float4*)(src + i);
  float4 b = *(const float4*)(src + i + 4);
  bf16x8 v;
  v[0] = (bf16_t)a.x; v[1] = (bf16_t)a.y; v[2] = (bf16_t)a.z; v[3] = (bf16_t)a.w;
  v[4] = (bf16_t)b.x; v[5] = (bf16_t)b.y; v[6] = (bf16_t)b.z; v[7] = (bf16_t)b.w;
  *(bf16x8*)(dst + i) = v;
}

// C = A @ B^T, LDS-staged (m93-style). A: M x K row-major. B: N x K row-major.
// TRANS==0: C = M x N row-major (dtype OUT). TRANS==1: C = N x M (C^T).
// Block 256 thr / 4 waves (2x2). Block tile 128x64, BK=32, wave tile 64x32.
// 2-barrier K-loop with register prefetch of the next stage.
template<int TRANS, typename OUT>
__global__ __launch_bounds__(256) void gemm_nt(const bf16_t* __restrict__ A,
                                               const bf16_t* __restrict__ B,
                                               OUT* __restrict__ C,
                                               int M, int N, int K) {
  __shared__ __align__(16) bf16_t As[BM * APITCH];  // 10240 B
  __shared__ __align__(16) bf16_t Bs[BN * APITCH];  //  5120 B

  const int tid  = threadIdx.x;
  const int wid  = tid >> 6;
  const int lane = tid & 63;
  const int lr   = lane & 15;
  const int quad = lane >> 4;
  const int wm = wid >> 1, wn = wid & 1;
  const int m0 = blockIdx.y * BM;
  const int n0 = blockIdx.x * BN;

  // A staging: thread t -> row t>>1 (0..127), k-offset (t&1)*16, 32 B (2x bf16x8)
  const int ar = tid >> 1, ak = (tid & 1) * 16;
  const bf16_t* ag = A + (size_t)(m0 + ar) * K + ak;
  // B staging: thread t -> row t>>2 (0..63), k-offset (t&3)*8, 16 B
  const int br = tid >> 2, bk = (tid & 3) * 8;
  const bf16_t* bg = B + (size_t)(n0 + br) * K + bk;

  floatx4 acc[4][2];
#pragma unroll
  for (int i = 0; i < 4; ++i)
#pragma unroll
    for (int j = 0; j < 2; ++j) acc[i][j] = floatx4{0.f, 0.f, 0.f, 0.f};

  // Prefetch iter 0
  bf16x8 pa0 = *(const bf16x8*)(ag);
  bf16x8 pa1 = *(const bf16x8*)(ag + 8);
  bf16x8 pb  = *(const bf16x8*)(bg);

  for (int kb = 0; kb < K; kb += BK) {
    __syncthreads();   // previous iteration's LDS reads complete
    *(bf16x8*)(As + ar * APITCH + ak)     = pa0;
    *(bf16x8*)(As + ar * APITCH + ak + 8) = pa1;
    *(bf16x8*)(Bs + br * APITCH + bk)     = pb;
    __syncthreads();

    if (kb + BK < K) {   // prefetch next stage into registers
      pa0 = *(const bf16x8*)(ag + kb + BK);
      pa1 = *(const bf16x8*)(ag + kb + BK + 8);
      pb  = *(const bf16x8*)(bg + kb + BK);
    }

    bf16x8 af[4], bfr[2];
#pragma unroll
    for (int i = 0; i < 4; ++i)
      af[i] = *(const bf16x8*)(As + (wm * 64 + i * 16 + lr) * APITCH + quad * 8);
#pragma unroll
    for (int j = 0; j < 2; ++j)
      bfr[j] = *(const bf16x8*)(Bs + (wn * 32 + j * 16 + lr) * APITCH + quad * 8);

#pragma unroll
    for (int i = 0; i < 4; ++i)
#pragma unroll
      for (int j = 0; j < 2; ++j)
        acc[i][j] = mfma16(af[i], bfr[j], acc[i][j]);
  }

#pragma unroll
  for (int i = 0; i < 4; ++i)
#pragma unroll
    for (int j = 0; j < 2; ++j)
#pragma unroll
      for (int r = 0; r < 4; ++r) {
        int row = m0 + wm * 64 + i * 16 + quad * 4 + r;
        int col = n0 + wn * 32 + j * 16 + lr;
        OUT v = (OUT)acc[i][j][r];
        if (TRANS == 0)
          C[(size_t)row * N + col] = v;
        else
          C[(size_t)col * M + row] = v;
      }
}

// In-place RoPE on Q and K (S x 1024 bf16). Auto-detects int32/int64 positions.
__global__ __launch_bounds__(256) void rope_kernel(bf16_t* __restrict__ Q,
                                                   bf16_t* __restrict__ K,
                                                   const void* __restrict__ posv) {
  int idx = blockIdx.x * blockDim.x + threadIdx.x;
  if (idx >= S_LEN * 512) return;
  int s   = idx >> 9;
  int rem = idx & 511;
  int h   = rem >> 5;
  int j   = rem & 31;
  size_t off = (size_t)s * DMODEL + h * DK + 2 * j;

  const long long* p64 = (const long long*)posv;
  const int*       p32 = (const int*)posv;
  unsigned long long w0 = (unsigned long long)p64[0];
  unsigned long long w1 = (unsigned long long)p64[1];
  bool is64 = ((w0 >> 32) == 0ull) && ((w1 >> 32) == 0ull);
  int safe_idx = is64 ? s : 0;
  long long v64 = p64[safe_idx];
  float p = is64 ? (float)v64 : (float)p32[s];

  float inv_freq = expf(-(float)j * (9.210340371976184f / 32.0f));
  float ang = p * inv_freq;
  float sn, cs;
  sincosf(ang, &sn, &cs);

  float q1 = (float)Q[off], q2 = (float)Q[off + 1];
  Q[off]     = (bf16_t)(q1 * cs - q2 * sn);
  Q[off + 1] = (bf16_t)(q1 * sn + q2 * cs);

  float k1 = (float)K[off], k2 = (float)K[off + 1];
  K[off]     = (bf16_t)(k1 * cs - k2 * sn);
  K[off + 1] = (bf16_t)(k1 * sn + k2 * cs);
}

// Flash attention, causal, streaming softmax, kv-parallel (r9 structure,
// 254 us measured). Block = (head, 16 q-rows); 4 waves split kv round-robin,
// merge once through LDS at the end.
__global__ __launch_bounds__(256) void attn_kernel(const bf16_t* __restrict__ Q,
                                                   const bf16_t* __restrict__ Kb,
                                                   const bf16_t* __restrict__ Vt,
                                                   bf16_t* __restrict__ O) {
  __shared__ __align__(16) bf16_t Pl[4][16 * KPITCH];
  __shared__ float Ored[4][16][OPITCH];
  __shared__ float lsFull[4][16];

  const int tid  = threadIdx.x;
  const int wid  = tid >> 6;
  const int lane = tid & 63;
  const int lr   = lane & 15;
  const int quad = lane >> 4;

  const int bid = blockIdx.x;
  const int h   = bid & 15;
  const int qt  = 255 - (bid >> 4);
  const int q0  = qt * 16;
  const int total_ch = (qt >> 2) + 1;

  const bf16_t* Qp = Q + (size_t)(q0 + lr) * DMODEL + h * DK + quad * 8;
  bf16x8 qf0 = *(const bf16x8*)(Qp);
  bf16x8 qf1 = *(const bf16x8*)(Qp + 32);

  floatx4 o0 = {0.f, 0.f, 0.f, 0.f};
  floatx4 o1 = o0, o2 = o0, o3 = o0;
  float lsum[4] = {0.f, 0.f, 0.f, 0.f};

  const bf16_t* Kh = Kb + h * DK;
  const bf16_t* Vh = Vt + (size_t)h * DK * S_LEN;
  bf16_t* Pw = &Pl[wid][0];

  for (int c = wid; c < total_ch; c += 4) {
    const int kvb = c * 64;
    const bool masked = (c == total_ch - 1);

    floatx4 s[4];
#pragma unroll
    for (int f = 0; f < 4; ++f) {
      const bf16_t* Kf = Kh + (size_t)(kvb + f * 16 + lr) * DMODEL + quad * 8;
      floatx4 z = {0.f, 0.f, 0.f, 0.f};
      z = mfma16(qf0, *(const bf16x8*)(Kf), z);
      s[f] = mfma16(qf1, *(const bf16x8*)(Kf + 32), z);
    }

#pragma unroll
    for (int f = 0; f < 4; ++f) {
#pragma unroll
      for (int r = 0; r < 4; ++r) {
        float p = exp2f(s[f][r] * SCALE_LOG2E);
        if (masked) {
          int kv   = kvb + f * 16 + lr;
          int qrow = q0 + quad * 4 + r;
          p = (kv <= qrow) ? p : 0.f;
        }
        s[f][r] = p;
        lsum[r] += p;
      }
    }

#pragma unroll
    for (int f = 0; f < 4; ++f) {
#pragma unroll
      for (int r = 0; r < 4; ++r) {
        Pw[(quad * 4 + r) * KPITCH + f * 16 + lr] = (bf16_t)s[f][r];
      }
    }
    __asm__ volatile("s_waitcnt lgkmcnt(0)" ::: "memory");
    bf16x8 pf0 = *(const bf16x8*)(Pw + lr * KPITCH + quad * 8);
    bf16x8 pf1 = *(const bf16x8*)(Pw + lr * KPITCH + 32 + quad * 8);

    const bf16_t* vp = Vh + (size_t)lr * S_LEN + kvb + quad * 8;
    o0 = mfma16(pf0, *(const bf16x8*)(vp), o0);
    o0 = mfma16(pf1, *(const bf16x8*)(vp + 32), o0);
    const bf16_t* vp1 = vp + (size_t)16 * S_LEN;
    o1 = mfma16(pf0, *(const bf16x8*)(vp1), o1);
    o1 = mfma16(pf1, *(const bf16x8*)(vp1 + 32), o1);
    const bf16_t* vp2 = vp + (size_t)32 * S_LEN;
    o2 = mfma16(pf0, *(const bf16x8*)(vp2), o2);
    o2 = mfma16(pf1, *(const bf16x8*)(vp2 + 32), o2);
    const bf16_t* vp3 = vp + (size_t)48 * S_LEN;
    o3 = mfma16(pf0, *(const bf16x8*)(vp3), o3);
    o3 = mfma16(pf1, *(const bf16x8*)(vp3 + 32), o3);
  }

#pragma unroll
  for (int m = 1; m < 16; m <<= 1) {
#pragma unroll
    for (int r = 0; r < 4; ++r) lsum[r] += __shfl_xor(lsum[r], m, 64);
  }

  floatx4 oo[4] = {o0, o1, o2, o3};
#pragma unroll
  for (int dt = 0; dt < 4; ++dt) {
#pragma unroll
    for (int r = 0; r < 4; ++r) {
      Ored[wid][quad * 4 + r][dt * 16 + lr] = oo[dt][r];
    }
  }
  if (lr == 0) {
#pragma unroll
    for (int r = 0; r < 4; ++r) lsFull[wid][quad * 4 + r] = lsum[r];
  }
  __syncthreads();

#pragma unroll
  for (int rr = 0; rr < 4; ++rr) {
    int row = wid * 4 + rr;
    float acc = Ored[0][row][lane] + Ored[1][row][lane] +
                Ored[2][row][lane] + Ored[3][row][lane];
    float l = lsFull[0][row] + lsFull[1][row] + lsFull[2][row] + lsFull[3][row];
    O[(size_t)(q0 + row) * DMODEL + h * DK + lane] = (bf16_t)(acc / l);
  }
}

extern "C" void kernel_launch(void* const* d_in, const int* in_sizes, int n_in,
                              void* d_out, int out_size, void* d_ws, size_t ws_size,
                              hipStream_t stream) {
  const float* x  = (const float*)d_in[0];
  const float* Wq = (const float*)d_in[1];
  const float* Wk = (const float*)d_in[2];
  const float* Wv = (const float*)d_in[3];
  const float* Wo = (const float*)d_in[4];
  const void* pos = d_in[5];
  float* out = (float*)d_out;

  const size_t NELEM = (size_t)S_LEN * DMODEL;  // 4M elems
  const size_t WELEM = (size_t)DMODEL * DMODEL; // 1M elems

  bf16_t* xb = (bf16_t*)d_ws;   // 8 MB (later Ob)
  bf16_t* Qb = xb + NELEM;      // 8 MB
  bf16_t* Kb = Qb + NELEM;      // 8 MB
  bf16_t* Vt = Kb + NELEM;      // 8 MB
  bf16_t* Wb = Vt + NELEM;      // 2 MB (cycled per weight)
  bf16_t* Ob = xb;

  dim3 blk(256);
  dim3 gg(DMODEL / BN, S_LEN / BM);  // (16, 32) = 512 blocks
  int wsblocks = (int)(WELEM / 8 / 256);

  cvt_f32_bf16<<<(int)(NELEM / 8 / 256), blk, 0, stream>>>(x, xb, (int)NELEM);

  cvt_f32_bf16<<<wsblocks, blk, 0, stream>>>(Wq, Wb, (int)WELEM);
  gemm_nt<0, bf16_t><<<gg, blk, 0, stream>>>(xb, Wb, Qb, S_LEN, DMODEL, DMODEL);

  cvt_f32_bf16<<<wsblocks, blk, 0, stream>>>(Wk, Wb, (int)WELEM);
  gemm_nt<0, bf16_t><<<gg, blk, 0, stream>>>(xb, Wb, Kb, S_LEN, DMODEL, DMODEL);

  cvt_f32_bf16<<<wsblocks, blk, 0, stream>>>(Wv, Wb, (int)WELEM);
  gemm_nt<1, bf16_t><<<gg, blk, 0, stream>>>(xb, Wb, Vt, S_LEN, DMODEL, DMODEL);

  int npairs = S_LEN * 512;
  rope_kernel<<<(npairs + 255) / 256, blk, 0, stream>>>(Qb, Kb, pos);

  attn_kernel<<<NH * (S_LEN / 16), blk, 0, stream>>>(Qb, Kb, Vt, Ob);

  cvt_f32_bf16<<<wsblocks, blk, 0, stream>>>(Wo, Wb, (int)WELEM);
  gemm_nt<0, float><<<gg, blk, 0, stream>>>(Ob, Wb, out, S_LEN, DMODEL, DMODEL);
}

// Round 11
// 316.975 us; speedup vs baseline: 2.1481x; 1.2988x over previous
//
#include <hip/hip_runtime.h>
#include <hip/hip_bf16.h>
#include <math.h>

typedef __bf16 bf16_t;
typedef __bf16 bf16x8 __attribute__((ext_vector_type(8)));
typedef float floatx4 __attribute__((ext_vector_type(4)));

#define S_LEN 4096
#define DMODEL 1024
#define NH 16
#define DK 64
// 0.125 (1/sqrt(dk)) * log2(e): p = exp2(dot * SCALE_LOG2E) == exp(dot/8)
#define SCALE_LOG2E 0.1803368801111204f
#define KPITCH 68   // attn P-transpose pitch: measured ZERO LDS conflicts (r7-r10)
#define OPITCH 65   // attn merge pitch: worst 2-way (free)

// GEMM tile params (r10-validated: 128x64, BK=32, pitch 40)
#define BM 128
#define BN 64
#define BK 32
#define APITCH 40

static __device__ __forceinline__ floatx4 mfma16(bf16x8 a, bf16x8 b, floatx4 c) {
  return __builtin_amdgcn_mfma_f32_16x16x32_bf16(a, b, c, 0, 0, 0);
}

// fp32 -> bf16 elementwise convert (n multiple of 8).
__global__ __launch_bounds__(256) void cvt_f32_bf16(const float* __restrict__ src,
                                                    bf16_t* __restrict__ dst, int n) {
  int i = (blockIdx.x * blockDim.x + threadIdx.x) * 8;
  if (i >= n) return;
  float4 a = *(const float4*)(src + i);
  float4 b = *(const float4*)(src + i + 4);
  bf16x8 v;
  v[0] = (bf16_t)a.x; v[1] = (bf16_t)a.y; v[2] = (bf16_t)a.z; v[3] = (bf16_t)a.w;
  v[4] = (bf16_t)b.x; v[5] = (bf16_t)b.y; v[6] = (bf16_t)b.z; v[7] = (bf16_t)b.w;
  *(bf16x8*)(dst + i) = v;
}

// C = A @ B^T, LDS-staged (r10-validated structure). A: M x K row-major bf16.
// B: N x K row-major FP32 (converted to bf16 in-register during staging —
// same RNE cast as the old cvt kernel). TRANS==0: C = M x N (dtype OUT);
// TRANS==1: C = N x M. Block 256 thr / 4 waves (2x2), tile 128x64, BK=32.
template<int TRANS, typename OUT>
__global__ __launch_bounds__(256) void gemm_nt(const bf16_t* __restrict__ A,
                                               const float* __restrict__ B,
                                               OUT* __restrict__ C,
                                               int M, int N, int K) {
  __shared__ __align__(16) bf16_t As[BM * APITCH];
  __shared__ __align__(16) bf16_t Bs[BN * APITCH];

  const int tid  = threadIdx.x;
  const int wid  = tid >> 6;
  const int lane = tid & 63;
  const int lr   = lane & 15;
  const int quad = lane >> 4;
  const int wm = wid >> 1, wn = wid & 1;
  const int m0 = blockIdx.y * BM;
  const int n0 = blockIdx.x * BN;

  // A staging: thread t -> row t>>1 (0..127), k-offset (t&1)*16, 32 B
  const int ar = tid >> 1, ak = (tid & 1) * 16;
  const bf16_t* ag = A + (size_t)(m0 + ar) * K + ak;
  // B staging: thread t -> row t>>2 (0..63), k-offset (t&3)*8, 8 fp32 (32 B)
  const int br = tid >> 2, bk = (tid & 3) * 8;
  const float* bg = B + (size_t)(n0 + br) * K + bk;

  floatx4 acc[4][2];
#pragma unroll
  for (int i = 0; i < 4; ++i)
#pragma unroll
    for (int j = 0; j < 2; ++j) acc[i][j] = floatx4{0.f, 0.f, 0.f, 0.f};

  // Prefetch iter 0
  bf16x8 pa0 = *(const bf16x8*)(ag);
  bf16x8 pa1 = *(const bf16x8*)(ag + 8);
  float4 pb0 = *(const float4*)(bg);
  float4 pb1 = *(const float4*)(bg + 4);

  for (int kb = 0; kb < K; kb += BK) {
    bf16x8 pbv;
    pbv[0] = (bf16_t)pb0.x; pbv[1] = (bf16_t)pb0.y;
    pbv[2] = (bf16_t)pb0.z; pbv[3] = (bf16_t)pb0.w;
    pbv[4] = (bf16_t)pb1.x; pbv[5] = (bf16_t)pb1.y;
    pbv[6] = (bf16_t)pb1.z; pbv[7] = (bf16_t)pb1.w;

    __syncthreads();
    *(bf16x8*)(As + ar * APITCH + ak)     = pa0;
    *(bf16x8*)(As + ar * APITCH + ak + 8) = pa1;
    *(bf16x8*)(Bs + br * APITCH + bk)     = pbv;
    __syncthreads();

    if (kb + BK < K) {
      pa0 = *(const bf16x8*)(ag + kb + BK);
      pa1 = *(const bf16x8*)(ag + kb + BK + 8);
      pb0 = *(const float4*)(bg + kb + BK);
      pb1 = *(const float4*)(bg + kb + BK + 4);
    }

    bf16x8 af[4], bfr[2];
#pragma unroll
    for (int i = 0; i < 4; ++i)
      af[i] = *(const bf16x8*)(As + (wm * 64 + i * 16 + lr) * APITCH + quad * 8);
#pragma unroll
    for (int j = 0; j < 2; ++j)
      bfr[j] = *(const bf16x8*)(Bs + (wn * 32 + j * 16 + lr) * APITCH + quad * 8);

#pragma unroll
    for (int i = 0; i < 4; ++i)
#pragma unroll
      for (int j = 0; j < 2; ++j)
        acc[i][j] = mfma16(af[i], bfr[j], acc[i][j]);
  }

#pragma unroll
  for (int i = 0; i < 4; ++i)
#pragma unroll
    for (int j = 0; j < 2; ++j)
#pragma unroll
      for (int r = 0; r < 4; ++r) {
        int row = m0 + wm * 64 + i * 16 + quad * 4 + r;
        int col = n0 + wn * 32 + j * 16 + lr;
        OUT v = (OUT)acc[i][j][r];
        if (TRANS == 0)
          C[(size_t)row * N + col] = v;
        else
          C[(size_t)col * M + row] = v;
      }
}

// In-place RoPE on Q and K (S x 1024 bf16). Auto-detects int32/int64 positions.
__global__ __launch_bounds__(256) void rope_kernel(bf16_t* __restrict__ Q,
                                                   bf16_t* __restrict__ K,
                                                   const void* __restrict__ posv) {
  int idx = blockIdx.x * blockDim.x + threadIdx.x;
  if (idx >= S_LEN * 512) return;
  int s   = idx >> 9;
  int rem = idx & 511;
  int h   = rem >> 5;
  int j   = rem & 31;
  size_t off = (size_t)s * DMODEL + h * DK + 2 * j;

  const long long* p64 = (const long long*)posv;
  const int*       p32 = (const int*)posv;
  unsigned long long w0 = (unsigned long long)p64[0];
  unsigned long long w1 = (unsigned long long)p64[1];
  bool is64 = ((w0 >> 32) == 0ull) && ((w1 >> 32) == 0ull);
  int safe_idx = is64 ? s : 0;
  long long v64 = p64[safe_idx];
  float p = is64 ? (float)v64 : (float)p32[s];

  float inv_freq = expf(-(float)j * (9.210340371976184f / 32.0f));
  float ang = p * inv_freq;
  float sn, cs;
  sincosf(ang, &sn, &cs);

  float q1 = (float)Q[off], q2 = (float)Q[off + 1];
  Q[off]     = (bf16_t)(q1 * cs - q2 * sn);
  Q[off + 1] = (bf16_t)(q1 * sn + q2 * cs);

  float k1 = (float)K[off], k2 = (float)K[off + 1];
  K[off]     = (bf16_t)(k1 * cs - k2 * sn);
  K[off + 1] = (bf16_t)(k1 * sn + k2 * cs);
}

// Flash attention, causal, streaming softmax (validated r7-r10), kv-parallel,
// now 32 q-rows per wave: each wave holds TWO Q fragments and reuses every
// K/V gather for both (2 MFMAs per gather vs 1 in r9). Block = (head, 32
// q-rows); 4 waves split kv chunks round-robin; merge once via LDS overlay.
// Q,K: S x 1024 row-major. Vt: 1024 x S (V^T). Grid: NH*(S/32) = 2048 blocks.
__global__ __launch_bounds__(256) void attn_kernel(const bf16_t* __restrict__ Q,
                                                   const bf16_t* __restrict__ Kb,
                                                   const bf16_t* __restrict__ Vt,
                                                   bf16_t* __restrict__ O) {
  // Overlay: loop phase uses P transpose buffers (4 waves x 32 rows x KPITCH
  // bf16 = 17408 B); merge phase reuses the same memory as Ored[4][32][OPITCH]
  // f32 (33280 B) + lsFull[4][32] f32 (512 B). Barrier-separated.
  __shared__ __align__(16) unsigned char smem[4 * 32 * OPITCH * 4 + 4 * 32 * 4];

  const int tid  = threadIdx.x;
  const int wid  = tid >> 6;
  const int lane = tid & 63;
  const int lr   = lane & 15;
  const int quad = lane >> 4;

  const int bid = blockIdx.x;
  const int h   = bid & 15;
  const int qt  = 127 - (bid >> 4);     // heavy q-tiles scheduled first
  const int q0  = qt * 32;
  const int total_ch = (q0 + 32 + 63) >> 6;   // 64-kv chunks covering [0, q0+32)

  // Two Q fragments per wave (rows q0+lr and q0+16+lr)
  bf16x8 qf[2][2];
#pragma unroll
  for (int t = 0; t < 2; ++t) {
    const bf16_t* Qp = Q + (size_t)(q0 + t * 16 + lr) * DMODEL + h * DK + quad * 8;
    qf[t][0] = *(const bf16x8*)(Qp);
    qf[t][1] = *(const bf16x8*)(Qp + 32);
  }

  floatx4 o[2][4];
#pragma unroll
  for (int t = 0; t < 2; ++t)
#pragma unroll
    for (int dt = 0; dt < 4; ++dt) o[t][dt] = floatx4{0.f, 0.f, 0.f, 0.f};
  float lsum[2][4] = {{0.f, 0.f, 0.f, 0.f}, {0.f, 0.f, 0.f, 0.f}};

  const bf16_t* Kh = Kb + h * DK;
  const bf16_t* Vh = Vt + (size_t)h * DK * S_LEN;
  bf16_t* Pw = (bf16_t*)smem + wid * 32 * KPITCH;

  for (int c = wid; c < total_ch; c += 4) {
    const int kvb = c * 64;
    const bool masked = (c == total_ch - 1);

    // K gathers once, reused by both q-fragments
    bf16x8 kf[4][2];
#pragma unroll
    for (int f = 0; f < 4; ++f) {
      const bf16_t* Kf = Kh + (size_t)(kvb + f * 16 + lr) * DMODEL + quad * 8;
      kf[f][0] = *(const bf16x8*)(Kf);
      kf[f][1] = *(const bf16x8*)(Kf + 32);
    }

    // QK^T: 2 q-frags x 4 kv-frags x 2 dk-halves = 16 MFMAs
    floatx4 s[2][4];
#pragma unroll
    for (int t = 0; t < 2; ++t) {
#pragma unroll
      for (int f = 0; f < 4; ++f) {
        floatx4 z = {0.f, 0.f, 0.f, 0.f};
        z = mfma16(qf[t][0], kf[f][0], z);
        s[t][f] = mfma16(qf[t][1], kf[f][1], z);
      }
    }

    // exp + causal mask (diagonal chunk only) + lsum; P -> LDS
#pragma unroll
    for (int t = 0; t < 2; ++t) {
#pragma unroll
      for (int f = 0; f < 4; ++f) {
#pragma unroll
        for (int r = 0; r < 4; ++r) {
          float p = exp2f(s[t][f][r] * SCALE_LOG2E);
          if (masked) {
            int kv   = kvb + f * 16 + lr;
            int qrow = q0 + t * 16 + quad * 4 + r;
            p = (kv <= qrow) ? p : 0.f;
          }
          s[t][f][r] = p;
          lsum[t][r] += p;
          Pw[(t * 16 + quad * 4 + r) * KPITCH + f * 16 + lr] = (bf16_t)p;
        }
      }
    }
    __asm__ volatile("s_waitcnt lgkmcnt(0)" ::: "memory");

    bf16x8 pf[2][2];
#pragma unroll
    for (int t = 0; t < 2; ++t) {
      pf[t][0] = *(const bf16x8*)(Pw + (t * 16 + lr) * KPITCH + quad * 8);
      pf[t][1] = *(const bf16x8*)(Pw + (t * 16 + lr) * KPITCH + 32 + quad * 8);
    }

    // V gathers once, reused by both q-fragments; PV: 16 MFMAs
#pragma unroll
    for (int dt = 0; dt < 4; ++dt) {
      const bf16_t* vp = Vh + (size_t)(dt * 16 + lr) * S_LEN + kvb + quad * 8;
      bf16x8 v0 = *(const bf16x8*)(vp);
      bf16x8 v1 = *(const bf16x8*)(vp + 32);
#pragma unroll
      for (int t = 0; t < 2; ++t) {
        o[t][dt] = mfma16(pf[t][0], v0, o[t][dt]);
        o[t][dt] = mfma16(pf[t][1], v1, o[t][dt]);
      }
    }
  }

  // Wave-local reduce of lsum over the 16 lr lanes
#pragma unroll
  for (int m = 1; m < 16; m <<= 1) {
#pragma unroll
    for (int t = 0; t < 2; ++t)
#pragma unroll
      for (int r = 0; r < 4; ++r) lsum[t][r] += __shfl_xor(lsum[t][r], m, 64);
  }

  __syncthreads();  // all waves done with P buffers; reuse smem as merge buffer

  float* Ored  = (float*)smem;                 // [4][32][OPITCH]
  float* lsF   = (float*)smem + 4 * 32 * OPITCH;  // [4][32]
#pragma unroll
  for (int t = 0; t < 2; ++t) {
#pragma unroll
    for (int dt = 0; dt < 4; ++dt) {
#pragma unroll
      for (int r = 0; r < 4; ++r) {
        Ored[(wid * 32 + t * 16 + quad * 4 + r) * OPITCH + dt * 16 + lr] = o[t][dt][r];
      }
    }
  }
  if (lr == 0) {
#pragma unroll
    for (int t = 0; t < 2; ++t)
#pragma unroll
      for (int r = 0; r < 4; ++r)
        lsF[wid * 32 + t * 16 + quad * 4 + r] = lsum[t][r];
  }
  __syncthreads();

  // Merge: wave wid handles rows wid*8..wid*8+7; lane = column 0..63
#pragma unroll
  for (int rr = 0; rr < 8; ++rr) {
    int row = wid * 8 + rr;
    float acc = Ored[(0 * 32 + row) * OPITCH + lane] +
                Ored[(1 * 32 + row) * OPITCH + lane] +
                Ored[(2 * 32 + row) * OPITCH + lane] +
                Ored[(3 * 32 + row) * OPITCH + lane];
    float l = lsF[0 * 32 + row] + lsF[1 * 32 + row] +
              lsF[2 * 32 + row] + lsF[3 * 32 + row];
    O[(size_t)(q0 + row) * DMODEL + h * DK + lane] = (bf16_t)(acc / l);
  }
}

extern "C" void kernel_launch(void* const* d_in, const int* in_sizes, int n_in,
                              void* d_out, int out_size, void* d_ws, size_t ws_size,
                              hipStream_t stream) {
  const float* x  = (const float*)d_in[0];
  const float* Wq = (const float*)d_in[1];
  const float* Wk = (const float*)d_in[2];
  const float* Wv = (const float*)d_in[3];
  const float* Wo = (const float*)d_in[4];
  const void* pos = d_in[5];
  float* out = (float*)d_out;

  const size_t NELEM = (size_t)S_LEN * DMODEL;  // 4M elems

  // Workspace: 32 MB. xb reused as Ob after attn inputs are built.
  bf16_t* xb = (bf16_t*)d_ws;   // 8 MB (later Ob)
  bf16_t* Qb = xb + NELEM;      // 8 MB
  bf16_t* Kb = Qb + NELEM;      // 8 MB
  bf16_t* Vt = Kb + NELEM;      // 8 MB
  bf16_t* Ob = xb;

  dim3 blk(256);
  dim3 gg(DMODEL / BN, S_LEN / BM);  // (16, 32) = 512 blocks

  cvt_f32_bf16<<<(int)(NELEM / 8 / 256), blk, 0, stream>>>(x, xb, (int)NELEM);

  gemm_nt<0, bf16_t><<<gg, blk, 0, stream>>>(xb, Wq, Qb, S_LEN, DMODEL, DMODEL);
  gemm_nt<0, bf16_t><<<gg, blk, 0, stream>>>(xb, Wk, Kb, S_LEN, DMODEL, DMODEL);
  gemm_nt<1, bf16_t><<<gg, blk, 0, stream>>>(xb, Wv, Vt, S_LEN, DMODEL, DMODEL);

  int npairs = S_LEN * 512;
  rope_kernel<<<(npairs + 255) / 256, blk, 0, stream>>>(Qb, Kb, pos);

  // 2048 blocks: (head, 32 q-rows) each; 4 waves split kv
  attn_kernel<<<NH * (S_LEN / 32), blk, 0, stream>>>(Qb, Kb, Vt, Ob);

  gemm_nt<0, float><<<gg, blk, 0, stream>>>(Ob, Wo, out, S_LEN, DMODEL, DMODEL);
}

// Round 12
// 304.910 us; speedup vs baseline: 2.2331x; 1.0396x over previous
//
#include <hip/hip_runtime.h>
#include <hip/hip_bf16.h>
#include <math.h>

typedef __bf16 bf16_t;
typedef __bf16 bf16x8 __attribute__((ext_vector_type(8)));
typedef float floatx4 __attribute__((ext_vector_type(4)));

#define S_LEN 4096
#define DMODEL 1024
#define NH 16
#define DK 64
// 0.125 (1/sqrt(dk)) * log2(e): p = exp2(dot * SCALE_LOG2E) == exp(dot/8)
#define SCALE_LOG2E 0.1803368801111204f
#define KPITCH 68   // attn P-transpose pitch: measured ZERO conflicts (r7-r11)

// GEMM tile params (r10/r11-validated: 128x64, BK=32, pitch 40)
#define BM 128
#define BN 64
#define BK 32
#define APITCH 40

static __device__ __forceinline__ floatx4 mfma16(bf16x8 a, bf16x8 b, floatx4 c) {
  return __builtin_amdgcn_mfma_f32_16x16x32_bf16(a, b, c, 0, 0, 0);
}

// fp32 -> bf16 elementwise convert (n multiple of 8).
__global__ __launch_bounds__(256) void cvt_f32_bf16(const float* __restrict__ src,
                                                    bf16_t* __restrict__ dst, int n) {
  int i = (blockIdx.x * blockDim.x + threadIdx.x) * 8;
  if (i >= n) return;
  float4 a = *(const float4*)(src + i);
  float4 b = *(const float4*)(src + i + 4);
  bf16x8 v;
  v[0] = (bf16_t)a.x; v[1] = (bf16_t)a.y; v[2] = (bf16_t)a.z; v[3] = (bf16_t)a.w;
  v[4] = (bf16_t)b.x; v[5] = (bf16_t)b.y; v[6] = (bf16_t)b.z; v[7] = (bf16_t)b.w;
  *(bf16x8*)(dst + i) = v;
}

// FUSED QKV GEMM: one dispatch computes Q = x@Wq^T, K = x@Wk^T, Vt = (x@Wv^T)^T.
// blockIdx.x: 0..15 -> Q cols, 16..31 -> K cols, 32..47 -> V cols (transposed
// store). x: M x Kd bf16. W*: N x Kd fp32 (RNE-cast to bf16 during staging).
// Block 256 thr / 4 waves (2x2), tile 128x64, BK=32, register prefetch.
__global__ __launch_bounds__(256) void qkv_gemm(const bf16_t* __restrict__ A,
                                                const float* __restrict__ Wq,
                                                const float* __restrict__ Wk,
                                                const float* __restrict__ Wv,
                                                bf16_t* __restrict__ Qo,
                                                bf16_t* __restrict__ Ko,
                                                bf16_t* __restrict__ Vo,
                                                int M, int N, int Kd) {
  __shared__ __align__(16) bf16_t As[BM * APITCH];
  __shared__ __align__(16) bf16_t Bs[BN * APITCH];

  const int tid  = threadIdx.x;
  const int wid  = tid >> 6;
  const int lane = tid & 63;
  const int lr   = lane & 15;
  const int quad = lane >> 4;
  const int wm = wid >> 1, wn = wid & 1;
  const int sel = blockIdx.x >> 4;              // 0=Q, 1=K, 2=V
  const int n0  = (blockIdx.x & 15) * BN;
  const int m0  = blockIdx.y * BM;
  const float* B = (sel == 0) ? Wq : ((sel == 1) ? Wk : Wv);

  const int ar = tid >> 1, ak = (tid & 1) * 16;
  const bf16_t* ag = A + (size_t)(m0 + ar) * Kd + ak;
  const int br = tid >> 2, bk = (tid & 3) * 8;
  const float* bg = B + (size_t)(n0 + br) * Kd + bk;

  floatx4 acc[4][2];
#pragma unroll
  for (int i = 0; i < 4; ++i)
#pragma unroll
    for (int j = 0; j < 2; ++j) acc[i][j] = floatx4{0.f, 0.f, 0.f, 0.f};

  bf16x8 pa0 = *(const bf16x8*)(ag);
  bf16x8 pa1 = *(const bf16x8*)(ag + 8);
  float4 pb0 = *(const float4*)(bg);
  float4 pb1 = *(const float4*)(bg + 4);

  for (int kb = 0; kb < Kd; kb += BK) {
    bf16x8 pbv;
    pbv[0] = (bf16_t)pb0.x; pbv[1] = (bf16_t)pb0.y;
    pbv[2] = (bf16_t)pb0.z; pbv[3] = (bf16_t)pb0.w;
    pbv[4] = (bf16_t)pb1.x; pbv[5] = (bf16_t)pb1.y;
    pbv[6] = (bf16_t)pb1.z; pbv[7] = (bf16_t)pb1.w;

    __syncthreads();
    *(bf16x8*)(As + ar * APITCH + ak)     = pa0;
    *(bf16x8*)(As + ar * APITCH + ak + 8) = pa1;
    *(bf16x8*)(Bs + br * APITCH + bk)     = pbv;
    __syncthreads();

    if (kb + BK < Kd) {
      pa0 = *(const bf16x8*)(ag + kb + BK);
      pa1 = *(const bf16x8*)(ag + kb + BK + 8);
      pb0 = *(const float4*)(bg + kb + BK);
      pb1 = *(const float4*)(bg + kb + BK + 4);
    }

    bf16x8 af[4], bfr[2];
#pragma unroll
    for (int i = 0; i < 4; ++i)
      af[i] = *(const bf16x8*)(As + (wm * 64 + i * 16 + lr) * APITCH + quad * 8);
#pragma unroll
    for (int j = 0; j < 2; ++j)
      bfr[j] = *(const bf16x8*)(Bs + (wn * 32 + j * 16 + lr) * APITCH + quad * 8);

#pragma unroll
    for (int i = 0; i < 4; ++i)
#pragma unroll
      for (int j = 0; j < 2; ++j)
        acc[i][j] = mfma16(af[i], bfr[j], acc[i][j]);
  }

  bf16_t* Cn = (sel == 0) ? Qo : Ko;
#pragma unroll
  for (int i = 0; i < 4; ++i)
#pragma unroll
    for (int j = 0; j < 2; ++j)
#pragma unroll
      for (int r = 0; r < 4; ++r) {
        int row = m0 + wm * 64 + i * 16 + quad * 4 + r;
        int col = n0 + wn * 32 + j * 16 + lr;
        bf16_t v = (bf16_t)acc[i][j][r];
        if (sel < 2)
          Cn[(size_t)row * N + col] = v;
        else
          Vo[(size_t)col * M + row] = v;
      }
}

// Final GEMM: C(fp32) = A(bf16) @ B(fp32->bf16)^T. Same r10 structure.
__global__ __launch_bounds__(256) void gemm_out(const bf16_t* __restrict__ A,
                                                const float* __restrict__ B,
                                                float* __restrict__ C,
                                                int M, int N, int Kd) {
  __shared__ __align__(16) bf16_t As[BM * APITCH];
  __shared__ __align__(16) bf16_t Bs[BN * APITCH];

  const int tid  = threadIdx.x;
  const int wid  = tid >> 6;
  const int lane = tid & 63;
  const int lr   = lane & 15;
  const int quad = lane >> 4;
  const int wm = wid >> 1, wn = wid & 1;
  const int m0 = blockIdx.y * BM;
  const int n0 = blockIdx.x * BN;

  const int ar = tid >> 1, ak = (tid & 1) * 16;
  const bf16_t* ag = A + (size_t)(m0 + ar) * Kd + ak;
  const int br = tid >> 2, bk = (tid & 3) * 8;
  const float* bg = B + (size_t)(n0 + br) * Kd + bk;

  floatx4 acc[4][2];
#pragma unroll
  for (int i = 0; i < 4; ++i)
#pragma unroll
    for (int j = 0; j < 2; ++j) acc[i][j] = floatx4{0.f, 0.f, 0.f, 0.f};

  bf16x8 pa0 = *(const bf16x8*)(ag);
  bf16x8 pa1 = *(const bf16x8*)(ag + 8);
  float4 pb0 = *(const float4*)(bg);
  float4 pb1 = *(const float4*)(bg + 4);

  for (int kb = 0; kb < Kd; kb += BK) {
    bf16x8 pbv;
    pbv[0] = (bf16_t)pb0.x; pbv[1] = (bf16_t)pb0.y;
    pbv[2] = (bf16_t)pb0.z; pbv[3] = (bf16_t)pb0.w;
    pbv[4] = (bf16_t)pb1.x; pbv[5] = (bf16_t)pb1.y;
    pbv[6] = (bf16_t)pb1.z; pbv[7] = (bf16_t)pb1.w;

    __syncthreads();
    *(bf16x8*)(As + ar * APITCH + ak)     = pa0;
    *(bf16x8*)(As + ar * APITCH + ak + 8) = pa1;
    *(bf16x8*)(Bs + br * APITCH + bk)     = pbv;
    __syncthreads();

    if (kb + BK < Kd) {
      pa0 = *(const bf16x8*)(ag + kb + BK);
      pa1 = *(const bf16x8*)(ag + kb + BK + 8);
      pb0 = *(const float4*)(bg + kb + BK);
      pb1 = *(const float4*)(bg + kb + BK + 4);
    }

    bf16x8 af[4], bfr[2];
#pragma unroll
    for (int i = 0; i < 4; ++i)
      af[i] = *(const bf16x8*)(As + (wm * 64 + i * 16 + lr) * APITCH + quad * 8);
#pragma unroll
    for (int j = 0; j < 2; ++j)
      bfr[j] = *(const bf16x8*)(Bs + (wn * 32 + j * 16 + lr) * APITCH + quad * 8);

#pragma unroll
    for (int i = 0; i < 4; ++i)
#pragma unroll
      for (int j = 0; j < 2; ++j)
        acc[i][j] = mfma16(af[i], bfr[j], acc[i][j]);
  }

#pragma unroll
  for (int i = 0; i < 4; ++i)
#pragma unroll
    for (int j = 0; j < 2; ++j)
#pragma unroll
      for (int r = 0; r < 4; ++r) {
        int row = m0 + wm * 64 + i * 16 + quad * 4 + r;
        int col = n0 + wn * 32 + j * 16 + lr;
        C[(size_t)row * N + col] = acc[i][j][r];
      }
}

// In-place RoPE on Q and K (S x 1024 bf16). Auto-detects int32/int64 positions.
__global__ __launch_bounds__(256) void rope_kernel(bf16_t* __restrict__ Q,
                                                   bf16_t* __restrict__ K,
                                                   const void* __restrict__ posv) {
  int idx = blockIdx.x * blockDim.x + threadIdx.x;
  if (idx >= S_LEN * 512) return;
  int s   = idx >> 9;
  int rem = idx & 511;
  int h   = rem >> 5;
  int j   = rem & 31;
  size_t off = (size_t)s * DMODEL + h * DK + 2 * j;

  const long long* p64 = (const long long*)posv;
  const int*       p32 = (const int*)posv;
  unsigned long long w0 = (unsigned long long)p64[0];
  unsigned long long w1 = (unsigned long long)p64[1];
  bool is64 = ((w0 >> 32) == 0ull) && ((w1 >> 32) == 0ull);
  int safe_idx = is64 ? s : 0;
  long long v64 = p64[safe_idx];
  float p = is64 ? (float)v64 : (float)p32[s];

  float inv_freq = expf(-(float)j * (9.210340371976184f / 32.0f));
  float ang = p * inv_freq;
  float sn, cs;
  sincosf(ang, &sn, &cs);

  float q1 = (float)Q[off], q2 = (float)Q[off + 1];
  Q[off]     = (bf16_t)(q1 * cs - q2 * sn);
  Q[off + 1] = (bf16_t)(q1 * sn + q2 * cs);

  float k1 = (float)K[off], k2 = (float)K[off + 1];
  K[off]     = (bf16_t)(k1 * cs - k2 * sn);
  K[off + 1] = (bf16_t)(k1 * sn + k2 * cs);
}

// Flash attention, causal, streaming softmax, kv-parallel, 32 q-rows/wave
// (r11 structure, 148 us). LDS halved: merge buffer is now bf16 at pitch 68,
// overlaying the P region exactly (17408 B each) -> 17.9 KB/block, LDS cap
// 8 blocks/CU (vs 4 in r11). Grid: NH*(S/32) = 2048 blocks.
__global__ __launch_bounds__(256) void attn_kernel(const bf16_t* __restrict__ Q,
                                                   const bf16_t* __restrict__ Kb,
                                                   const bf16_t* __restrict__ Vt,
                                                   bf16_t* __restrict__ O) {
  __shared__ __align__(16) unsigned char smem[4 * 32 * KPITCH * 2 + 4 * 32 * 4];

  const int tid  = threadIdx.x;
  const int wid  = tid >> 6;
  const int lane = tid & 63;
  const int lr   = lane & 15;
  const int quad = lane >> 4;

  const int bid = blockIdx.x;
  const int h   = bid & 15;
  const int qt  = 127 - (bid >> 4);     // heavy q-tiles scheduled first
  const int q0  = qt * 32;
  const int total_ch = (q0 + 32 + 63) >> 6;   // 64-kv chunks covering [0, q0+32)

  bf16x8 qf[2][2];
#pragma unroll
  for (int t = 0; t < 2; ++t) {
    const bf16_t* Qp = Q + (size_t)(q0 + t * 16 + lr) * DMODEL + h * DK + quad * 8;
    qf[t][0] = *(const bf16x8*)(Qp);
    qf[t][1] = *(const bf16x8*)(Qp + 32);
  }

  floatx4 o[2][4];
#pragma unroll
  for (int t = 0; t < 2; ++t)
#pragma unroll
    for (int dt = 0; dt < 4; ++dt) o[t][dt] = floatx4{0.f, 0.f, 0.f, 0.f};
  float lsum[2][4] = {{0.f, 0.f, 0.f, 0.f}, {0.f, 0.f, 0.f, 0.f}};

  const bf16_t* Kh = Kb + h * DK;
  const bf16_t* Vh = Vt + (size_t)h * DK * S_LEN;
  bf16_t* Pw = (bf16_t*)smem + wid * 32 * KPITCH;

  for (int c = wid; c < total_ch; c += 4) {
    const int kvb = c * 64;
    const bool masked = (c == total_ch - 1);

    bf16x8 kf[4][2];
#pragma unroll
    for (int f = 0; f < 4; ++f) {
      const bf16_t* Kf = Kh + (size_t)(kvb + f * 16 + lr) * DMODEL + quad * 8;
      kf[f][0] = *(const bf16x8*)(Kf);
      kf[f][1] = *(const bf16x8*)(Kf + 32);
    }

    floatx4 s[2][4];
#pragma unroll
    for (int t = 0; t < 2; ++t) {
#pragma unroll
      for (int f = 0; f < 4; ++f) {
        floatx4 z = {0.f, 0.f, 0.f, 0.f};
        z = mfma16(qf[t][0], kf[f][0], z);
        s[t][f] = mfma16(qf[t][1], kf[f][1], z);
      }
    }

#pragma unroll
    for (int t = 0; t < 2; ++t) {
#pragma unroll
      for (int f = 0; f < 4; ++f) {
#pragma unroll
        for (int r = 0; r < 4; ++r) {
          float p = exp2f(s[t][f][r] * SCALE_LOG2E);
          if (masked) {
            int kv   = kvb + f * 16 + lr;
            int qrow = q0 + t * 16 + quad * 4 + r;
            p = (kv <= qrow) ? p : 0.f;
          }
          lsum[t][r] += p;
          Pw[(t * 16 + quad * 4 + r) * KPITCH + f * 16 + lr] = (bf16_t)p;
        }
      }
    }
    __asm__ volatile("s_waitcnt lgkmcnt(0)" ::: "memory");

    bf16x8 pf[2][2];
#pragma unroll
    for (int t = 0; t < 2; ++t) {
      pf[t][0] = *(const bf16x8*)(Pw + (t * 16 + lr) * KPITCH + quad * 8);
      pf[t][1] = *(const bf16x8*)(Pw + (t * 16 + lr) * KPITCH + 32 + quad * 8);
    }

#pragma unroll
    for (int dt = 0; dt < 4; ++dt) {
      const bf16_t* vp = Vh + (size_t)(dt * 16 + lr) * S_LEN + kvb + quad * 8;
      bf16x8 v0 = *(const bf16x8*)(vp);
      bf16x8 v1 = *(const bf16x8*)(vp + 32);
#pragma unroll
      for (int t = 0; t < 2; ++t) {
        o[t][dt] = mfma16(pf[t][0], v0, o[t][dt]);
        o[t][dt] = mfma16(pf[t][1], v1, o[t][dt]);
      }
    }
  }

#pragma unroll
  for (int m = 1; m < 16; m <<= 1) {
#pragma unroll
    for (int t = 0; t < 2; ++t)
#pragma unroll
      for (int r = 0; r < 4; ++r) lsum[t][r] += __shfl_xor(lsum[t][r], m, 64);
  }

  __syncthreads();  // all waves done with P buffers; overlay as merge buffer

  bf16_t* OredB = (bf16_t*)smem;                       // [4][32][KPITCH] bf16
  float*  lsF   = (float*)(smem + 4 * 32 * KPITCH * 2); // [4][32] f32
#pragma unroll
  for (int t = 0; t < 2; ++t) {
#pragma unroll
    for (int dt = 0; dt < 4; ++dt) {
#pragma unroll
      for (int r = 0; r < 4; ++r) {
        OredB[(wid * 32 + t * 16 + quad * 4 + r) * KPITCH + dt * 16 + lr] =
            (bf16_t)o[t][dt][r];
      }
    }
  }
  if (lr == 0) {
#pragma unroll
    for (int t = 0; t < 2; ++t)
#pragma unroll
      for (int r = 0; r < 4; ++r)
        lsF[wid * 32 + t * 16 + quad * 4 + r] = lsum[t][r];
  }
  __syncthreads();

  // Merge: wave wid handles rows wid*8..wid*8+7; lane = column 0..63
#pragma unroll
  for (int rr = 0; rr < 8; ++rr) {
    int row = wid * 8 + rr;
    float acc = (float)OredB[(0 * 32 + row) * KPITCH + lane] +
                (float)OredB[(1 * 32 + row) * KPITCH + lane] +
                (float)OredB[(2 * 32 + row) * KPITCH + lane] +
                (float)OredB[(3 * 32 + row) * KPITCH + lane];
    float l = lsF[0 * 32 + row] + lsF[1 * 32 + row] +
              lsF[2 * 32 + row] + lsF[3 * 32 + row];
    O[(size_t)(q0 + row) * DMODEL + h * DK + lane] = (bf16_t)(acc / l);
  }
}

extern "C" void kernel_launch(void* const* d_in, const int* in_sizes, int n_in,
                              void* d_out, int out_size, void* d_ws, size_t ws_size,
                              hipStream_t stream) {
  const float* x  = (const float*)d_in[0];
  const float* Wq = (const float*)d_in[1];
  const float* Wk = (const float*)d_in[2];
  const float* Wv = (const float*)d_in[3];
  const float* Wo = (const float*)d_in[4];
  const void* pos = d_in[5];
  float* out = (float*)d_out;

  const size_t NELEM = (size_t)S_LEN * DMODEL;  // 4M elems

  bf16_t* xb = (bf16_t*)d_ws;   // 8 MB (later Ob)
  bf16_t* Qb = xb + NELEM;      // 8 MB
  bf16_t* Kb = Qb + NELEM;      // 8 MB
  bf16_t* Vt = Kb + NELEM;      // 8 MB
  bf16_t* Ob = xb;

  dim3 blk(256);

  cvt_f32_bf16<<<(int)(NELEM / 8 / 256), blk, 0, stream>>>(x, xb, (int)NELEM);

  // Fused QKV: 48 x 32 = 1536 blocks (6/CU)
  dim3 gq(3 * DMODEL / BN, S_LEN / BM);
  qkv_gemm<<<gq, blk, 0, stream>>>(xb, Wq, Wk, Wv, Qb, Kb, Vt,
                                   S_LEN, DMODEL, DMODEL);

  int npairs = S_LEN * 512;
  rope_kernel<<<(npairs + 255) / 256, blk, 0, stream>>>(Qb, Kb, pos);

  attn_kernel<<<NH * (S_LEN / 32), blk, 0, stream>>>(Qb, Kb, Vt, Ob);

  dim3 gg(DMODEL / BN, S_LEN / BM);  // (16, 32)
  gemm_out<<<gg, blk, 0, stream>>>(Ob, Wo, out, S_LEN, DMODEL, DMODEL);
}